// Round 6
// baseline (608.510 us; speedup 1.0000x reference)
//
#include <hip/hip_runtime.h>
#include <math.h>
#include <float.h>

#define NN 50000
#define EE 800000
#define FF 64
#define EDIM 16
#define GG 64
#define NB64 782   // ceil(NN/64)
#define NSB 196    // ceil(NN/256) scan blocks

typedef short bf16x8 __attribute__((ext_vector_type(8)));
typedef float f32x4 __attribute__((ext_vector_type(4)));

__device__ inline unsigned short bf_rne(float v) {
  unsigned int u = __float_as_uint(v);
  unsigned int r = (u + 0x7FFFu + ((u >> 16) & 1u)) >> 16;
  return (unsigned short)r;
}
__device__ inline float bf_up(unsigned short h) {
  return __uint_as_float(((unsigned int)h) << 16);
}
__device__ inline void split4(float4 v, ushort4& h, ushort4& l) {
  h.x = bf_rne(v.x); h.y = bf_rne(v.y); h.z = bf_rne(v.z); h.w = bf_rne(v.w);
  l.x = bf_rne(v.x - bf_up(h.x));
  l.y = bf_rne(v.y - bf_up(h.y));
  l.z = bf_rne(v.z - bf_up(h.z));
  l.w = bf_rne(v.w - bf_up(h.w));
}
__device__ inline float blo(unsigned int u) { return __uint_as_float(u << 16); }
__device__ inline float bhi(unsigned int u) { return __uint_as_float(u & 0xFFFF0000u); }

// ---------------------------------------------------------------- degree
__global__ void k_deg(const int* __restrict__ eidx, int* __restrict__ deg) {
  int e = blockIdx.x * 256 + threadIdx.x;
  if (e < EE) atomicAdd(&deg[eidx[EE + e]], 1);
}

// ---------------------------------------------------------------- scan pass A
__global__ __launch_bounds__(256) void k_scanA(const int* __restrict__ deg, int* __restrict__ offsets,
                                               int* __restrict__ bsum, float* __restrict__ lsum) {
  __shared__ int ws[4];
  __shared__ float lw[4];
  int t = threadIdx.x;
  int lane = t & 63;
  int wv = t >> 6;
  int i = blockIdx.x * 256 + t;
  int v = (i < NN) ? deg[i] : 0;
  float lg = (i < NN) ? logf((float)v + 1.0f) : 0.0f;
  int x = v;
  #pragma unroll
  for (int o = 1; o < 64; o <<= 1) {
    int y = __shfl_up(x, o);
    if (lane >= o) x += y;
  }
  #pragma unroll
  for (int o = 1; o < 64; o <<= 1) lg += __shfl_xor(lg, o);
  if (lane == 63) ws[wv] = x;
  if (lane == 0) lw[wv] = lg;
  __syncthreads();
  int pre = 0;
  for (int k = 0; k < wv; k++) pre += ws[k];
  if (i < NN) offsets[i] = pre + x - v;
  if (t == 0) {
    bsum[blockIdx.x] = ws[0] + ws[1] + ws[2] + ws[3];
    lsum[blockIdx.x] = lw[0] + lw[1] + lw[2] + lw[3];
  }
}

// ---------------------------------------------------------------- scan pass B
__global__ __launch_bounds__(256) void k_scanB(const int* __restrict__ bsum, const float* __restrict__ lsum,
                                               int* __restrict__ bpref, float* __restrict__ meta,
                                               float* __restrict__ scbA) {
  __shared__ int ws[4];
  __shared__ float lw[4];
  int t = threadIdx.x;
  int lane = t & 63;
  int wv = t >> 6;
  int v = (t < NSB) ? bsum[t] : 0;
  float lg = (t < NSB) ? lsum[t] : 0.0f;
  int x = v;
  #pragma unroll
  for (int o = 1; o < 64; o <<= 1) {
    int y = __shfl_up(x, o);
    if (lane >= o) x += y;
  }
  #pragma unroll
  for (int o = 1; o < 64; o <<= 1) lg += __shfl_xor(lg, o);
  if (lane == 63) ws[wv] = x;
  if (lane == 0) lw[wv] = lg;
  __syncthreads();
  int pre = 0;
  for (int k = 0; k < wv; k++) pre += ws[k];
  if (t < NSB) bpref[t] = pre + x - v;
  if (t == 0) meta[0] = (lw[0] + lw[1] + lw[2] + lw[3]) / (float)NN;
  if (t < 64) { scbA[t] = 1.0f; scbA[64 + t] = 0.0f; }
  if (t == 0) scbA[128] = -FLT_MAX;
}

// ---------------------------------------------------------------- scan pass C
__global__ __launch_bounds__(256) void k_scanC(int* __restrict__ offsets, const int* __restrict__ bpref,
                                               const int* __restrict__ deg, const float* __restrict__ meta,
                                               float* __restrict__ amp, float* __restrict__ att) {
  int i = blockIdx.x * 256 + threadIdx.x;
  if (i < NN) {
    offsets[i] += bpref[blockIdx.x];
    float d = (float)deg[i];
    float avg = meta[0];
    float logd = logf(fmaxf(d, 1.0f) + 1.0f);
    amp[i] = logd / avg;
    att[i] = avg / logd;
  }
  if (i == 0) offsets[NN] = EE;
}

// ---------------------------------------------------------------- scatter + permute eattr (bf16)
__global__ void k_scatter(const int* __restrict__ eidx, const int* __restrict__ offsets,
                          int* __restrict__ cursor, int* __restrict__ srcs,
                          const float* __restrict__ eattr, unsigned int* __restrict__ PermEA) {
  int e = blockIdx.x * 256 + threadIdx.x;
  if (e < EE) {
    int s = eidx[e];
    int d = eidx[EE + e];
    int pos = offsets[d] + atomicAdd(&cursor[d], 1);
    srcs[pos] = s;
    const float4* ep = (const float4*)(eattr + (size_t)e * EDIM);
    float4 q0 = ep[0], q1 = ep[1], q2 = ep[2], q3 = ep[3];
    uint4 pa, pb;
    pa.x = (unsigned)bf_rne(q0.x) | ((unsigned)bf_rne(q0.y) << 16);
    pa.y = (unsigned)bf_rne(q0.z) | ((unsigned)bf_rne(q0.w) << 16);
    pa.z = (unsigned)bf_rne(q1.x) | ((unsigned)bf_rne(q1.y) << 16);
    pa.w = (unsigned)bf_rne(q1.z) | ((unsigned)bf_rne(q1.w) << 16);
    pb.x = (unsigned)bf_rne(q2.x) | ((unsigned)bf_rne(q2.y) << 16);
    pb.y = (unsigned)bf_rne(q2.z) | ((unsigned)bf_rne(q2.w) << 16);
    pb.z = (unsigned)bf_rne(q3.x) | ((unsigned)bf_rne(q3.y) << 16);
    pb.w = (unsigned)bf_rne(q3.z) | ((unsigned)bf_rne(q3.w) << 16);
    ((uint4*)PermEA)[(size_t)pos * 2] = pa;
    ((uint4*)PermEA)[(size_t)pos * 2 + 1] = pb;
  }
}

// ---------------------------------------------------------------- per-layer prep
__global__ __launch_bounds__(256) void k_prep2(const float* __restrict__ We, const float* __restrict__ be,
                                               const float* __restrict__ Wpre, const float* __restrict__ bpre,
                                               const float* __restrict__ Wpost, const float* __restrict__ bpost,
                                               const float* __restrict__ Wlin, const float* __restrict__ blin,
                                               unsigned short* __restrict__ MwT_h, unsigned short* __restrict__ MwT_l,
                                               float* __restrict__ bconst,
                                               unsigned short* __restrict__ WcT_h, unsigned short* __restrict__ WcT_l,
                                               unsigned short* __restrict__ WxT_h, unsigned short* __restrict__ WxT_l,
                                               float* __restrict__ bcomb) {
  int id = blockIdx.x * 256 + threadIdx.x;
  if (id < 53248) {                      // WcombT
    int k = id >> 6, f = id & 63;
    float a = 0.0f;
    for (int j = 0; j < FF; j++) a += Wpost[(size_t)k * FF + j] * Wlin[j * FF + f];
    unsigned short h = bf_rne(a);
    WcT_h[f * 832 + k] = h;
    WcT_l[f * 832 + k] = bf_rne(a - bf_up(h));
  } else if (id < 61440) {               // WxT
    int lid = id - 53248;
    int j = lid >> 6, k = lid & 63;
    float v = (j < 64) ? Wpre[k * FF + j] : Wpre[(64 + k) * FF + (j - 64)];
    unsigned short h = bf_rne(v);
    WxT_h[j * 64 + k] = h;
    WxT_l[j * 64 + k] = bf_rne(v - bf_up(h));
  } else if (id < 62464) {               // MwT (bf16 hi/lo). Feature f=4*j+ct stored at tile ct, col j.
    int lid = id - 61440;
    int k = lid >> 6, f = lid & 63;
    float a = 0.0f;
    for (int j = 0; j < FF; j++) a += We[k * FF + j] * Wpre[(128 + j) * FF + f];
    unsigned short h = bf_rne(a);
    int ct = f & 3, jcol = f >> 2;
    MwT_h[(ct * 16 + jcol) * 16 + k] = h;
    MwT_l[(ct * 16 + jcol) * 16 + k] = bf_rne(a - bf_up(h));
  } else {                               // biases
    int f = threadIdx.x;
    if (blockIdx.x == 244 && f < 64) {
      float b = bpre[f];
      for (int j = 0; j < FF; j++) b += be[j] * Wpre[(128 + j) * FF + f];
      bconst[f] = b;
      float c = blin[f];
      for (int j = 0; j < FF; j++) c += bpost[j] * Wlin[j * FF + f];
      bcomb[f] = c;
    }
  }
}

// ---------------------------------------------------------------- [Xd|Xs] = bn(x) @ Wx via bf16x3 MFMA; Xs stored bf16
// B fragments loaded directly from global WxT (L2-resident); only A staged in LDS.
__global__ __launch_bounds__(256) void k_xform(const float* __restrict__ x, const float* __restrict__ scb,
                                               const unsigned short* __restrict__ WxT_h,
                                               const unsigned short* __restrict__ WxT_l,
                                               float* __restrict__ Xd, unsigned short* __restrict__ Xs) {
  __shared__ unsigned short Ah[64 * 72], Al[64 * 72];
  int t = threadIdx.x;
  int n0 = blockIdx.x * 64;
  {
    int r = t >> 2, c0 = (t & 3) * 16;
    int n = n0 + r;
    bool rok = n < NN;
    const float4* src = (const float4*)(x + (size_t)n * FF + c0);
    float flr = scb[128];
    #pragma unroll
    for (int c4 = 0; c4 < 4; c4++) {
      float4 v = rok ? src[c4] : make_float4(0.f, 0.f, 0.f, 0.f);
      float4 sc = ((const float4*)scb)[(c0 >> 2) + c4];
      float4 of = ((const float4*)(scb + 64))[(c0 >> 2) + c4];
      v.x = fmaxf(v.x * sc.x + of.x, flr);
      v.y = fmaxf(v.y * sc.y + of.y, flr);
      v.z = fmaxf(v.z * sc.z + of.z, flr);
      v.w = fmaxf(v.w * sc.w + of.w, flr);
      ushort4 h4, l4;
      split4(v, h4, l4);
      *(ushort4*)&Ah[r * 72 + c0 + c4 * 4] = h4;
      *(ushort4*)&Al[r * 72 + c0 + c4 * 4] = l4;
    }
  }
  __syncthreads();
  int lane = t & 63;
  int l15 = lane & 15;
  int quad = lane >> 4;
  int w = __builtin_amdgcn_readfirstlane(t >> 6);
  int rbase = (w & 1) * 32;
  int cbase = (w >> 1) * 64;
  f32x4 acc[2][4];
  #pragma unroll
  for (int rt = 0; rt < 2; rt++)
    #pragma unroll
    for (int ct = 0; ct < 4; ct++) acc[rt][ct] = (f32x4){0.f, 0.f, 0.f, 0.f};

  #pragma unroll
  for (int ks = 0; ks < 2; ks++) {
    bf16x8 a_h[2], a_l[2];
    #pragma unroll
    for (int rt = 0; rt < 2; rt++) {
      int row = rbase + rt * 16 + l15;
      a_h[rt] = *(const bf16x8*)&Ah[row * 72 + ks * 32 + quad * 8];
      a_l[rt] = *(const bf16x8*)&Al[row * 72 + ks * 32 + quad * 8];
    }
    #pragma unroll
    for (int ct = 0; ct < 4; ct++) {
      int col = cbase + ct * 16 + l15;
      bf16x8 b_h = *(const bf16x8*)(WxT_h + (size_t)col * 64 + ks * 32 + quad * 8);
      bf16x8 b_l = *(const bf16x8*)(WxT_l + (size_t)col * 64 + ks * 32 + quad * 8);
      #pragma unroll
      for (int rt = 0; rt < 2; rt++) {
        acc[rt][ct] = __builtin_amdgcn_mfma_f32_16x16x32_bf16(a_h[rt], b_h, acc[rt][ct], 0, 0, 0);
        acc[rt][ct] = __builtin_amdgcn_mfma_f32_16x16x32_bf16(a_h[rt], b_l, acc[rt][ct], 0, 0, 0);
        acc[rt][ct] = __builtin_amdgcn_mfma_f32_16x16x32_bf16(a_l[rt], b_h, acc[rt][ct], 0, 0, 0);
      }
    }
  }
  // store: cols 0..63 -> Xd (f32), 64..127 -> Xs (bf16)
  #pragma unroll
  for (int rt = 0; rt < 2; rt++) {
    #pragma unroll
    for (int ct = 0; ct < 4; ct++) {
      int col = cbase + ct * 16 + l15;
      #pragma unroll
      for (int reg = 0; reg < 4; reg++) {
        int n = n0 + rbase + rt * 16 + quad * 4 + reg;
        if (n < NN) {
          float v = acc[rt][ct][reg];
          if (col < 64) Xd[(size_t)n * FF + col] = v;
          else          Xs[(size_t)n * FF + (col - 64)] = bf_rne(v);
        }
      }
    }
  }
}

// ---------------------------------------------------------------- per-node CSR aggregation
// (round-3 best-measured version, 67.4 us)
// et = PermEA(bf16) @ Mw via MFMA (hi/lo B for f32-equivalent accuracy), kept entirely
// in registers: lane (quad,l15) owns edges quad*4+reg of each 16-edge tile and
// features f=4*l15+ct. Stats accumulate per-lane; one cross-quad shfl reduction per node.
__global__ __launch_bounds__(256) void k_agg(const int* __restrict__ srcs, const int* __restrict__ offsets,
                                             const unsigned int* __restrict__ PermEA,
                                             const unsigned short* __restrict__ MwT_h,
                                             const unsigned short* __restrict__ MwT_l,
                                             const float* __restrict__ bconst,
                                             const float* __restrict__ Xd, const unsigned short* __restrict__ Xs,
                                             unsigned short* __restrict__ aggs) {
  int wid = __builtin_amdgcn_readfirstlane(threadIdx.x >> 6);
  int lane = threadIdx.x & 63;
  int l15 = lane & 15;
  int quad = lane >> 4;
  int n = blockIdx.x * 4 + wid;
  if (n >= NN) return;

  bf16x8 bh[4], bl[4];
  #pragma unroll
  for (int ct = 0; ct < 4; ct++) {
    if (quad < 2) {
      bh[ct] = *(const bf16x8*)&MwT_h[(ct * 16 + l15) * 16 + quad * 8];
      bl[ct] = *(const bf16x8*)&MwT_l[(ct * 16 + l15) * 16 + quad * 8];
    } else {
      bh[ct] = (bf16x8){0, 0, 0, 0, 0, 0, 0, 0};
      bl[ct] = (bf16x8){0, 0, 0, 0, 0, 0, 0, 0};
    }
  }

  float4 xd4 = *(const float4*)(Xd + (size_t)n * FF + 4 * l15);
  float4 bc4 = *(const float4*)(bconst + 4 * l15);
  float bas[4] = {xd4.x + bc4.x, xd4.y + bc4.y, xd4.z + bc4.z, xd4.w + bc4.w};

  int o0 = offsets[n], o1 = offsets[n + 1];
  float s[4]  = {0.f, 0.f, 0.f, 0.f};
  float sq[4] = {0.f, 0.f, 0.f, 0.f};
  float mn[4] = {FLT_MAX, FLT_MAX, FLT_MAX, FLT_MAX};
  float mx[4] = {-FLT_MAX, -FLT_MAX, -FLT_MAX, -FLT_MAX};

  for (int base = o0; base < o1; base += 16) {
    bf16x8 af = (bf16x8){0, 0, 0, 0, 0, 0, 0, 0};
    if (quad < 2) af = *(const bf16x8*)(PermEA + (size_t)(base + l15) * 8 + quad * 4);
    f32x4 acc[4];
    #pragma unroll
    for (int ct = 0; ct < 4; ct++) {
      f32x4 a = (f32x4){0.f, 0.f, 0.f, 0.f};
      a = __builtin_amdgcn_mfma_f32_16x16x32_bf16(af, bl[ct], a, 0, 0, 0);
      a = __builtin_amdgcn_mfma_f32_16x16x32_bf16(af, bh[ct], a, 0, 0, 0);
      acc[ct] = a;
    }
    #pragma unroll
    for (int reg = 0; reg < 4; reg++) {
      int e = base + quad * 4 + reg;
      bool valid = e < o1;
      int ec = min(e, o1 - 1);
      int src = srcs[ec];
      ushort4 xs4 = *(const ushort4*)(Xs + (size_t)src * FF + 4 * l15);
      float xf[4] = {bf_up(xs4.x), bf_up(xs4.y), bf_up(xs4.z), bf_up(xs4.w)};
      #pragma unroll
      for (int ct = 0; ct < 4; ct++) {
        float h = bas[ct] + xf[ct] + acc[ct][reg];
        float hv = valid ? h : 0.0f;
        s[ct] += hv;
        sq[ct] = fmaf(hv, hv, sq[ct]);
        float t1 = fminf(mn[ct], h);
        float t2 = fmaxf(mx[ct], h);
        mn[ct] = valid ? t1 : mn[ct];
        mx[ct] = valid ? t2 : mx[ct];
      }
    }
  }

  #pragma unroll
  for (int ct = 0; ct < 4; ct++) {
    s[ct] += __shfl_xor(s[ct], 16);  s[ct] += __shfl_xor(s[ct], 32);
    sq[ct] += __shfl_xor(sq[ct], 16); sq[ct] += __shfl_xor(sq[ct], 32);
    mn[ct] = fminf(mn[ct], __shfl_xor(mn[ct], 16)); mn[ct] = fminf(mn[ct], __shfl_xor(mn[ct], 32));
    mx[ct] = fmaxf(mx[ct], __shfl_xor(mx[ct], 16)); mx[ct] = fmaxf(mx[ct], __shfl_xor(mx[ct], 32));
  }

  float d = (float)(o1 - o0);
  float dc = fmaxf(d, 1.0f);
  float rdc = 1.0f / dc;
  bool has = d > 0.0f;
  ushort4 outv;
  unsigned short ov[4];
  #pragma unroll
  for (int ct = 0; ct < 4; ct++) {
    float mean = s[ct] * rdc;
    float msq = sq[ct] * rdc;
    float sd = sqrtf(fmaxf(msq - mean * mean, 0.0f) + 1e-5f);
    float vmn = has ? mn[ct] : 0.0f;
    float vmx = has ? mx[ct] : 0.0f;
    float val = (quad == 0) ? mean : (quad == 1) ? vmn : (quad == 2) ? vmx : sd;
    ov[ct] = bf_rne(val);
  }
  outv.x = ov[0]; outv.y = ov[1]; outv.z = ov[2]; outv.w = ov[3];
  *(ushort4*)(aggs + (size_t)n * 256 + quad * 64 + 4 * l15) = outv;
}

// ---------------------------------------------------------------- y = [bn(x),scaled aggs] @ Wcomb + bcomb + BN partials
// Barrier-free after the x-chunk: A fragments for agg chunks load DIRECTLY from
// global aggs (raw bf16); B fragments load directly from WcT (L2-resident).
// amp/att deferred to epilogue via 3 accumulators: y = acc0 + amp*acc1 + att*acc2.
__global__ __launch_bounds__(256) void k_post(const float* __restrict__ x, const float* __restrict__ scb,
                                              const unsigned short* __restrict__ aggs,
                                              const float* __restrict__ amp, const float* __restrict__ att,
                                              const unsigned short* __restrict__ WcT_h,
                                              const unsigned short* __restrict__ WcT_l,
                                              const float* __restrict__ bcomb,
                                              float* __restrict__ y, float* __restrict__ partials) {
  __shared__ unsigned short Ah[64 * 72], Al[64 * 72];
  __shared__ float red_s[4][32], red_q[4][32];
  int t = threadIdx.x;
  int n0 = blockIdx.x * 64;
  int lane = t & 63;
  int l15 = lane & 15;
  int quad = lane >> 4;
  int w = __builtin_amdgcn_readfirstlane(t >> 6);
  int rbase = (w & 1) * 32;
  int cbase = (w >> 1) * 32;

  // stage bn(x) -> hi/lo bf16 fragments in LDS (thread->fragment transpose)
  {
    int ar = t >> 2;
    int ac0 = (t & 3) * 16;
    int an = n0 + ar;
    bool rok = an < NN;
    const float* xrow = x + (size_t)an * FF;
    float flr = scb[128];
    #pragma unroll
    for (int c4 = 0; c4 < 4; c4++) {
      float4 v = rok ? *(const float4*)(xrow + ac0 + c4 * 4) : make_float4(0.f, 0.f, 0.f, 0.f);
      float4 sc = ((const float4*)scb)[(ac0 >> 2) + c4];
      float4 of = ((const float4*)(scb + 64))[(ac0 >> 2) + c4];
      v.x = fmaxf(v.x * sc.x + of.x, flr);
      v.y = fmaxf(v.y * sc.y + of.y, flr);
      v.z = fmaxf(v.z * sc.z + of.z, flr);
      v.w = fmaxf(v.w * sc.w + of.w, flr);
      ushort4 h4, l4;
      split4(v, h4, l4);
      *(ushort4*)&Ah[ar * 72 + ac0 + c4 * 4] = h4;
      *(ushort4*)&Al[ar * 72 + ac0 + c4 * 4] = l4;
    }
  }
  __syncthreads();

  f32x4 acc[3][2][2];
  #pragma unroll
  for (int s = 0; s < 3; s++)
    #pragma unroll
    for (int rt = 0; rt < 2; rt++)
      #pragma unroll
      for (int ct = 0; ct < 2; ct++) acc[s][rt][ct] = (f32x4){0.f, 0.f, 0.f, 0.f};

  // x chunk (K rows 0..63 of WcT), full hi/lo precision
  #pragma unroll
  for (int ks = 0; ks < 2; ks++) {
    bf16x8 a_h[2], a_l[2];
    #pragma unroll
    for (int rt = 0; rt < 2; rt++) {
      int row = rbase + rt * 16 + l15;
      a_h[rt] = *(const bf16x8*)&Ah[row * 72 + ks * 32 + quad * 8];
      a_l[rt] = *(const bf16x8*)&Al[row * 72 + ks * 32 + quad * 8];
    }
    #pragma unroll
    for (int ct = 0; ct < 2; ct++) {
      int col = cbase + ct * 16 + l15;
      bf16x8 b_h = *(const bf16x8*)(WcT_h + (size_t)col * 832 + ks * 32 + quad * 8);
      bf16x8 b_l = *(const bf16x8*)(WcT_l + (size_t)col * 832 + ks * 32 + quad * 8);
      #pragma unroll
      for (int rt = 0; rt < 2; rt++) {
        acc[0][rt][ct] = __builtin_amdgcn_mfma_f32_16x16x32_bf16(a_h[rt], b_h, acc[0][rt][ct], 0, 0, 0);
        acc[0][rt][ct] = __builtin_amdgcn_mfma_f32_16x16x32_bf16(a_h[rt], b_l, acc[0][rt][ct], 0, 0, 0);
        acc[0][rt][ct] = __builtin_amdgcn_mfma_f32_16x16x32_bf16(a_l[rt], b_h, acc[0][rt][ct], 0, 0, 0);
      }
    }
  }

  // agg chunks c=0..3 (mean/min/max/std), scalings s=0..2 (1, amp, att)
  #pragma unroll
  for (int c = 0; c < 4; c++) {
    #pragma unroll
    for (int ks = 0; ks < 2; ks++) {
      bf16x8 a[2];
      #pragma unroll
      for (int rt = 0; rt < 2; rt++) {
        int row = n0 + rbase + rt * 16 + l15;
        row = min(row, NN - 1);   // junk rows only affect unstored outputs
        a[rt] = *(const bf16x8*)(aggs + (size_t)row * 256 + c * 64 + ks * 32 + quad * 8);
      }
      #pragma unroll
      for (int s = 0; s < 3; s++) {
        int kb = 64 + s * 256 + c * 64 + ks * 32 + quad * 8;
        #pragma unroll
        for (int ct = 0; ct < 2; ct++) {
          int col = cbase + ct * 16 + l15;
          bf16x8 b_h = *(const bf16x8*)(WcT_h + (size_t)col * 832 + kb);
          bf16x8 b_l = *(const bf16x8*)(WcT_l + (size_t)col * 832 + kb);
          #pragma unroll
          for (int rt = 0; rt < 2; rt++) {
            acc[s][rt][ct] = __builtin_amdgcn_mfma_f32_16x16x32_bf16(a[rt], b_h, acc[s][rt][ct], 0, 0, 0);
            acc[s][rt][ct] = __builtin_amdgcn_mfma_f32_16x16x32_bf16(a[rt], b_l, acc[s][rt][ct], 0, 0, 0);
          }
        }
      }
    }
  }

  // epilogue: combine scalings, bias, store y, BN partials
  float ps[2] = {0.f, 0.f}, pq[2] = {0.f, 0.f};
  float bc[2];
  #pragma unroll
  for (int ct = 0; ct < 2; ct++) bc[ct] = bcomb[cbase + ct * 16 + l15];
  #pragma unroll
  for (int rt = 0; rt < 2; rt++) {
    #pragma unroll
    for (int reg = 0; reg < 4; reg++) {
      int n = n0 + rbase + rt * 16 + quad * 4 + reg;
      bool ok = n < NN;
      int nc = min(n, NN - 1);
      float am = amp[nc];
      float at = att[nc];
      #pragma unroll
      for (int ct = 0; ct < 2; ct++) {
        float v = acc[0][rt][ct][reg] + am * acc[1][rt][ct][reg] + at * acc[2][rt][ct][reg] + bc[ct];
        if (ok) {
          y[(size_t)n * FF + (cbase + ct * 16 + l15)] = v;
          ps[ct] += v;
          pq[ct] += v * v;
        }
      }
    }
  }
  #pragma unroll
  for (int ct = 0; ct < 2; ct++) {
    ps[ct] += __shfl_xor(ps[ct], 16);
    ps[ct] += __shfl_xor(ps[ct], 32);
    pq[ct] += __shfl_xor(pq[ct], 16);
    pq[ct] += __shfl_xor(pq[ct], 32);
  }
  if (quad == 0) {
    #pragma unroll
    for (int ct = 0; ct < 2; ct++) {
      red_s[w][ct * 16 + l15] = ps[ct];
      red_q[w][ct * 16 + l15] = pq[ct];
    }
  }
  __syncthreads();
  if (t < 64) {
    float ss, qq;
    if (t < 32) { ss = red_s[0][t] + red_s[1][t]; qq = red_q[0][t] + red_q[1][t]; }
    else        { ss = red_s[2][t - 32] + red_s[3][t - 32]; qq = red_q[2][t - 32] + red_q[3][t - 32]; }
    partials[(size_t)blockIdx.x * 128 + t] = ss;
    partials[(size_t)blockIdx.x * 128 + 64 + t] = qq;
  }
}

// ---------------------------------------------------------------- reduce BN partials -> scb
__global__ __launch_bounds__(1024) void k_bnfin(const float* __restrict__ partials,
                                                const float* __restrict__ gamma, const float* __restrict__ beta,
                                                float* __restrict__ scb) {
  __shared__ float red[1024];
  __shared__ double tot[128];
  int t = threadIdx.x;
  int c = t & 127, seg = t >> 7;
  float s = 0.f;
  for (int i = seg; i < NB64; i += 8) s += partials[(size_t)i * 128 + c];
  red[t] = s;
  __syncthreads();
  if (t < 128) {
    double d = 0.0;
    #pragma unroll
    for (int sg = 0; sg < 8; sg++) d += (double)red[sg * 128 + t];
    tot[t] = d;
  }
  __syncthreads();
  if (t < 64) {
    double mu = tot[t] / (double)NN;
    double var = tot[64 + t] / (double)NN - mu * mu;
    float sc = gamma[t] * rsqrtf((float)fmax(var, 0.0) + 1e-5f);
    scb[t] = sc;
    scb[64 + t] = beta[t] - (float)mu * sc;
  }
  if (t == 0) scb[128] = 0.0f;
}

// ---------------------------------------------------------------- pooling (BN+relu fused)
__global__ __launch_bounds__(256) void k_pool(const float* __restrict__ x, const float* __restrict__ scb,
                                              const int* __restrict__ batch,
                                              float* __restrict__ psum, float* __restrict__ cnt) {
  int lane = threadIdx.x & 63;
  int wv = threadIdx.x >> 6;
  int wglobal = blockIdx.x * 4 + wv;
  int nw = gridDim.x * 4;
  int per = (NN + nw - 1) / nw;
  int n0 = wglobal * per;
  int n1 = min(n0 + per, NN);
  if (n0 >= n1) return;
  float sc = scb[lane], of = scb[64 + lane], flr = scb[128];
  int gcur = batch[n0];
  float acc = 0.0f;
  int count = 0;
  for (int n = n0; n < n1; n++) {
    int g = batch[n];
    float v = fmaxf(x[(size_t)n * FF + lane] * sc + of, flr);
    if (g != gcur) {
      atomicAdd(&psum[gcur * FF + lane], acc);
      if (lane == 0) atomicAdd(&cnt[gcur], (float)count);
      gcur = g; acc = 0.0f; count = 0;
    }
    acc += v;
    count++;
  }
  atomicAdd(&psum[gcur * FF + lane], acc);
  if (lane == 0) atomicAdd(&cnt[gcur], (float)count);
}

// ---------------------------------------------------------------- final MLP
__global__ void k_final(const float* __restrict__ psum, const float* __restrict__ cnt,
                        const float* __restrict__ W1, const float* __restrict__ b1,
                        const float* __restrict__ W2, const float* __restrict__ b2, float* __restrict__ out) {
  int g = threadIdx.x;
  if (g >= GG) return;
  float c = fmaxf(cnt[g], 1.0f);
  float gm[64];
  #pragma unroll
  for (int i = 0; i < 64; i++) gm[i] = psum[g * FF + i] / c;
  float o = b2[0];
  for (int h = 0; h < 40; h++) {
    float a = b1[h];
    #pragma unroll
    for (int i = 0; i < 64; i++) a += gm[i] * W1[i * 40 + h];
    o += fmaxf(a, 0.0f) * W2[h];
  }
  out[g] = o;
}

// ================================================================ launch
extern "C" void kernel_launch(void* const* d_in, const int* in_sizes, int n_in,
                              void* d_out, int out_size, void* d_ws, size_t ws_size,
                              hipStream_t stream) {
  (void)in_sizes; (void)n_in; (void)out_size; (void)ws_size;
  const float* x0    = (const float*)d_in[0];
  const float* eattr = (const float*)d_in[1];
  const float* We    = (const float*)d_in[2];
  const float* be    = (const float*)d_in[3];
  const float* Wpre  = (const float*)d_in[4];
  const float* bpre  = (const float*)d_in[5];
  const float* Wpost = (const float*)d_in[6];
  const float* bpost = (const float*)d_in[7];
  const float* Wlin  = (const float*)d_in[8];
  const float* blin  = (const float*)d_in[9];
  const float* gamma = (const float*)d_in[10];
  const float* beta  = (const float*)d_in[11];
  const float* W1    = (const float*)d_in[12];
  const float* b1    = (const float*)d_in[13];
  const float* W2    = (const float*)d_in[14];
  const float* b2    = (const float*)d_in[15];
  const int* eidx    = (const int*)d_in[16];
  const int* batch   = (const int*)d_in[17];
  float* out = (float*)d_out;

  char* w = (char*)d_ws;
  size_t off = 0;
  auto alloc = [&](size_t bytes) -> void* {
    void* p = w + off;
    off += bytes;
    off = (off + 255) & ~(size_t)255;
    return p;
  };
  int*    deg     = (int*)alloc(NN * sizeof(int));
  int*    offsets = (int*)alloc((NN + 1) * sizeof(int));
  int*    cursor  = (int*)alloc(NN * sizeof(int));
  int*    srcs    = (int*)alloc((EE + 16) * sizeof(int));
  unsigned int* PermEA = (unsigned int*)alloc(((size_t)EE + 16) * 8 * sizeof(unsigned int));
  int*    bsum    = (int*)alloc(NSB * sizeof(int));
  int*    bpref   = (int*)alloc(NSB * sizeof(int));
  float*  lsum    = (float*)alloc(NSB * sizeof(float));
  float*  meta    = (float*)alloc(sizeof(float));
  float*  amp     = (float*)alloc(NN * sizeof(float));
  float*  att     = (float*)alloc(NN * sizeof(float));
  unsigned short* MwT_h = (unsigned short*)alloc(FF * EDIM * sizeof(unsigned short));
  unsigned short* MwT_l = (unsigned short*)alloc(FF * EDIM * sizeof(unsigned short));
  float*  bconst  = (float*)alloc(FF * sizeof(float));
  float*  bcomb   = (float*)alloc(FF * sizeof(float));
  float*  scbA    = (float*)alloc(129 * sizeof(float));
  float*  scbB    = (float*)alloc(2 * 129 * sizeof(float));
  unsigned short* WcT_h = (unsigned short*)alloc(FF * 832 * sizeof(unsigned short));
  unsigned short* WcT_l = (unsigned short*)alloc(FF * 832 * sizeof(unsigned short));
  unsigned short* WxT_h = (unsigned short*)alloc(128 * 64 * sizeof(unsigned short));
  unsigned short* WxT_l = (unsigned short*)alloc(128 * 64 * sizeof(unsigned short));
  float*  partials = (float*)alloc((size_t)NB64 * 128 * sizeof(float));
  float*  Xd      = (float*)alloc((size_t)NN * FF * sizeof(float));
  unsigned short* Xs = (unsigned short*)alloc((size_t)NN * FF * sizeof(unsigned short));
  unsigned short* aggs = (unsigned short*)alloc((size_t)NN * 256 * sizeof(unsigned short));
  float*  ybuf    = (float*)alloc((size_t)NN * FF * sizeof(float));
  float*  psum    = (float*)alloc((GG * FF + GG) * sizeof(float));
  float*  cnt     = psum + GG * FF;

  hipMemsetAsync(deg, 0, NN * sizeof(int), stream);
  hipMemsetAsync(cursor, 0, NN * sizeof(int), stream);
  hipMemsetAsync(srcs + EE, 0, 16 * sizeof(int), stream);
  hipMemsetAsync(psum, 0, (GG * FF + GG) * sizeof(float), stream);

  k_deg<<<(EE + 255) / 256, 256, 0, stream>>>(eidx, deg);
  k_scanA<<<NSB, 256, 0, stream>>>(deg, offsets, bsum, lsum);
  k_scanB<<<1, 256, 0, stream>>>(bsum, lsum, bpref, meta, scbA);
  k_scanC<<<NSB, 256, 0, stream>>>(offsets, bpref, deg, meta, amp, att);
  k_scatter<<<(EE + 255) / 256, 256, 0, stream>>>(eidx, offsets, cursor, srcs, eattr, PermEA);

  const float* xin = x0;
  const float* scb_in = scbA;
  for (int l = 0; l < 2; l++) {
    k_prep2<<<245, 256, 0, stream>>>(We + l * EDIM * FF, be + l * FF, Wpre + (size_t)l * 3 * FF * FF,
                                     bpre + l * FF, Wpost + (size_t)l * 832 * FF, bpost + l * FF,
                                     Wlin + l * FF * FF, blin + l * FF,
                                     MwT_h, MwT_l, bconst, WcT_h, WcT_l, WxT_h, WxT_l, bcomb);
    k_xform<<<NB64, 256, 0, stream>>>(xin, scb_in, WxT_h, WxT_l, Xd, Xs);
    k_agg<<<(NN + 3) / 4, 256, 0, stream>>>(srcs, offsets, PermEA, MwT_h, MwT_l, bconst, Xd, Xs, aggs);
    k_post<<<NB64, 256, 0, stream>>>(xin, scb_in, aggs, amp, att, WcT_h, WcT_l, bcomb, ybuf, partials);
    k_bnfin<<<1, 1024, 0, stream>>>(partials, gamma + l * FF, beta + l * FF, scbB + l * 129);
    xin = ybuf;
    scb_in = scbB + l * 129;
  }
  k_pool<<<200, 256, 0, stream>>>(ybuf, scbB + 129, batch, psum, cnt);
  k_final<<<1, 64, 0, stream>>>(psum, cnt, W1, b1, W2, b2, out);
}

// Round 7
// 527.195 us; speedup vs baseline: 1.1542x; 1.1542x over previous
//
#include <hip/hip_runtime.h>
#include <math.h>
#include <float.h>

#define NN 50000
#define EE 800000
#define FF 64
#define EDIM 16
#define GG 64
#define NB64 782   // ceil(NN/64)
#define NSB 196    // ceil(NN/256) scan blocks

typedef short bf16x8 __attribute__((ext_vector_type(8)));
typedef float f32x4 __attribute__((ext_vector_type(4)));

__device__ inline unsigned short bf_rne(float v) {
  unsigned int u = __float_as_uint(v);
  unsigned int r = (u + 0x7FFFu + ((u >> 16) & 1u)) >> 16;
  return (unsigned short)r;
}
__device__ inline float bf_up(unsigned short h) {
  return __uint_as_float(((unsigned int)h) << 16);
}
__device__ inline void split4(float4 v, ushort4& h, ushort4& l) {
  h.x = bf_rne(v.x); h.y = bf_rne(v.y); h.z = bf_rne(v.z); h.w = bf_rne(v.w);
  l.x = bf_rne(v.x - bf_up(h.x));
  l.y = bf_rne(v.y - bf_up(h.y));
  l.z = bf_rne(v.z - bf_up(h.z));
  l.w = bf_rne(v.w - bf_up(h.w));
}

// ---------------------------------------------------------------- zero-fill (replaces 4 memsets)
__global__ __launch_bounds__(256) void k_zfill(int* __restrict__ deg, int* __restrict__ cursor,
                                               int* __restrict__ srcs_slack, float* __restrict__ psum) {
  int i = blockIdx.x * 256 + threadIdx.x;
  if (i < NN) { deg[i] = 0; cursor[i] = 0; }
  if (i < 16) srcs_slack[i] = 0;
  if (i < GG * FF + GG) psum[i] = 0.0f;
}

// ---------------------------------------------------------------- degree
__global__ void k_deg(const int* __restrict__ eidx, int* __restrict__ deg) {
  int e = blockIdx.x * 256 + threadIdx.x;
  if (e < EE) atomicAdd(&deg[eidx[EE + e]], 1);
}

// ---------------------------------------------------------------- scan pass A
__global__ __launch_bounds__(256) void k_scanA(const int* __restrict__ deg, int* __restrict__ offsets,
                                               int* __restrict__ bsum, float* __restrict__ lsum) {
  __shared__ int ws[4];
  __shared__ float lw[4];
  int t = threadIdx.x;
  int lane = t & 63;
  int wv = t >> 6;
  int i = blockIdx.x * 256 + t;
  int v = (i < NN) ? deg[i] : 0;
  float lg = (i < NN) ? logf((float)v + 1.0f) : 0.0f;
  int x = v;
  #pragma unroll
  for (int o = 1; o < 64; o <<= 1) {
    int y = __shfl_up(x, o);
    if (lane >= o) x += y;
  }
  #pragma unroll
  for (int o = 1; o < 64; o <<= 1) lg += __shfl_xor(lg, o);
  if (lane == 63) ws[wv] = x;
  if (lane == 0) lw[wv] = lg;
  __syncthreads();
  int pre = 0;
  for (int k = 0; k < wv; k++) pre += ws[k];
  if (i < NN) offsets[i] = pre + x - v;
  if (t == 0) {
    bsum[blockIdx.x] = ws[0] + ws[1] + ws[2] + ws[3];
    lsum[blockIdx.x] = lw[0] + lw[1] + lw[2] + lw[3];
  }
}

// ---------------------------------------------------------------- scan pass B
__global__ __launch_bounds__(256) void k_scanB(const int* __restrict__ bsum, const float* __restrict__ lsum,
                                               int* __restrict__ bpref, float* __restrict__ meta,
                                               float* __restrict__ scbA) {
  __shared__ int ws[4];
  __shared__ float lw[4];
  int t = threadIdx.x;
  int lane = t & 63;
  int wv = t >> 6;
  int v = (t < NSB) ? bsum[t] : 0;
  float lg = (t < NSB) ? lsum[t] : 0.0f;
  int x = v;
  #pragma unroll
  for (int o = 1; o < 64; o <<= 1) {
    int y = __shfl_up(x, o);
    if (lane >= o) x += y;
  }
  #pragma unroll
  for (int o = 1; o < 64; o <<= 1) lg += __shfl_xor(lg, o);
  if (lane == 63) ws[wv] = x;
  if (lane == 0) lw[wv] = lg;
  __syncthreads();
  int pre = 0;
  for (int k = 0; k < wv; k++) pre += ws[k];
  if (t < NSB) bpref[t] = pre + x - v;
  if (t == 0) meta[0] = (lw[0] + lw[1] + lw[2] + lw[3]) / (float)NN;
  if (t < 64) { scbA[t] = 1.0f; scbA[64 + t] = 0.0f; }
  if (t == 0) scbA[128] = -FLT_MAX;
}

// ---------------------------------------------------------------- scan pass C
__global__ __launch_bounds__(256) void k_scanC(int* __restrict__ offsets, const int* __restrict__ bpref,
                                               const int* __restrict__ deg, const float* __restrict__ meta,
                                               float* __restrict__ amp, float* __restrict__ att) {
  int i = blockIdx.x * 256 + threadIdx.x;
  if (i < NN) {
    offsets[i] += bpref[blockIdx.x];
    float d = (float)deg[i];
    float avg = meta[0];
    float logd = logf(fmaxf(d, 1.0f) + 1.0f);
    amp[i] = logd / avg;
    att[i] = avg / logd;
  }
  if (i == 0) offsets[NN] = EE;
}

// ---------------------------------------------------------------- scatter + permute eattr (bf16)
__global__ void k_scatter(const int* __restrict__ eidx, const int* __restrict__ offsets,
                          int* __restrict__ cursor, int* __restrict__ srcs,
                          const float* __restrict__ eattr, unsigned int* __restrict__ PermEA) {
  int e = blockIdx.x * 256 + threadIdx.x;
  if (e < EE) {
    int s = eidx[e];
    int d = eidx[EE + e];
    int pos = offsets[d] + atomicAdd(&cursor[d], 1);
    srcs[pos] = s;
    const float4* ep = (const float4*)(eattr + (size_t)e * EDIM);
    float4 q0 = ep[0], q1 = ep[1], q2 = ep[2], q3 = ep[3];
    uint4 pa, pb;
    pa.x = (unsigned)bf_rne(q0.x) | ((unsigned)bf_rne(q0.y) << 16);
    pa.y = (unsigned)bf_rne(q0.z) | ((unsigned)bf_rne(q0.w) << 16);
    pa.z = (unsigned)bf_rne(q1.x) | ((unsigned)bf_rne(q1.y) << 16);
    pa.w = (unsigned)bf_rne(q1.z) | ((unsigned)bf_rne(q1.w) << 16);
    pb.x = (unsigned)bf_rne(q2.x) | ((unsigned)bf_rne(q2.y) << 16);
    pb.y = (unsigned)bf_rne(q2.z) | ((unsigned)bf_rne(q2.w) << 16);
    pb.z = (unsigned)bf_rne(q3.x) | ((unsigned)bf_rne(q3.y) << 16);
    pb.w = (unsigned)bf_rne(q3.z) | ((unsigned)bf_rne(q3.w) << 16);
    ((uint4*)PermEA)[(size_t)pos * 2] = pa;
    ((uint4*)PermEA)[(size_t)pos * 2 + 1] = pb;
  }
}

// ---------------------------------------------------------------- per-layer prep (both layers in one dispatch)
__global__ __launch_bounds__(256) void k_prep2(const float* __restrict__ We, const float* __restrict__ be,
                                               const float* __restrict__ Wpre, const float* __restrict__ bpre,
                                               const float* __restrict__ Wpost, const float* __restrict__ bpost,
                                               const float* __restrict__ Wlin, const float* __restrict__ blin,
                                               unsigned short* __restrict__ MwT_h, unsigned short* __restrict__ MwT_l,
                                               float* __restrict__ bconst,
                                               unsigned short* __restrict__ WcT_h, unsigned short* __restrict__ WcT_l,
                                               unsigned short* __restrict__ WxT_h, unsigned short* __restrict__ WxT_l,
                                               float* __restrict__ bcomb) {
  int layer = blockIdx.x / 245;
  int blk = blockIdx.x % 245;
  We += (size_t)layer * EDIM * FF;  be += layer * FF;
  Wpre += (size_t)layer * 3 * FF * FF; bpre += layer * FF;
  Wpost += (size_t)layer * 832 * FF; bpost += layer * FF;
  Wlin += (size_t)layer * FF * FF; blin += layer * FF;
  MwT_h += layer * 1024; MwT_l += layer * 1024;
  bconst += layer * FF; bcomb += layer * FF;
  WcT_h += (size_t)layer * 53248; WcT_l += (size_t)layer * 53248;
  WxT_h += layer * 8192; WxT_l += layer * 8192;

  int id = blk * 256 + threadIdx.x;
  if (id < 53248) {                      // WcombT
    int k = id >> 6, f = id & 63;
    float a = 0.0f;
    for (int j = 0; j < FF; j++) a += Wpost[(size_t)k * FF + j] * Wlin[j * FF + f];
    unsigned short h = bf_rne(a);
    WcT_h[f * 832 + k] = h;
    WcT_l[f * 832 + k] = bf_rne(a - bf_up(h));
  } else if (id < 61440) {               // WxT
    int lid = id - 53248;
    int j = lid >> 6, k = lid & 63;
    float v = (j < 64) ? Wpre[k * FF + j] : Wpre[(64 + k) * FF + (j - 64)];
    unsigned short h = bf_rne(v);
    WxT_h[j * 64 + k] = h;
    WxT_l[j * 64 + k] = bf_rne(v - bf_up(h));
  } else if (id < 62464) {               // MwT (bf16 hi/lo). Feature f=4*j+ct stored at tile ct, col j.
    int lid = id - 61440;
    int k = lid >> 6, f = lid & 63;
    float a = 0.0f;
    for (int j = 0; j < FF; j++) a += We[k * FF + j] * Wpre[(128 + j) * FF + f];
    unsigned short h = bf_rne(a);
    int ct = f & 3, jcol = f >> 2;
    MwT_h[(ct * 16 + jcol) * 16 + k] = h;
    MwT_l[(ct * 16 + jcol) * 16 + k] = bf_rne(a - bf_up(h));
  } else {                               // biases
    int f = threadIdx.x;
    if (blk == 244 && f < 64) {
      float b = bpre[f];
      for (int j = 0; j < FF; j++) b += be[j] * Wpre[(128 + j) * FF + f];
      bconst[f] = b;
      float c = blin[f];
      for (int j = 0; j < FF; j++) c += bpost[j] * Wlin[j * FF + f];
      bcomb[f] = c;
    }
  }
}

// ---------------------------------------------------------------- [Xd|Xs] = bn(x) @ Wx via bf16x3 MFMA; Xs stored bf16
__global__ __launch_bounds__(256) void k_xform(const float* __restrict__ x, const float* __restrict__ scb,
                                               const unsigned short* __restrict__ WxT_h,
                                               const unsigned short* __restrict__ WxT_l,
                                               float* __restrict__ Xd, unsigned short* __restrict__ Xs) {
  __shared__ unsigned short Ah[64 * 72], Al[64 * 72];
  __shared__ unsigned short Bh[128 * 72], Bl[128 * 72];
  int t = threadIdx.x;
  int n0 = blockIdx.x * 64;
  {
    int j = t >> 1, half = t & 1;
    const ushort4* srch = (const ushort4*)(WxT_h + j * 64 + half * 32);
    const ushort4* srcl = (const ushort4*)(WxT_l + j * 64 + half * 32);
    #pragma unroll
    for (int i = 0; i < 8; i++) {
      *(ushort4*)&Bh[j * 72 + half * 32 + i * 4] = srch[i];
      *(ushort4*)&Bl[j * 72 + half * 32 + i * 4] = srcl[i];
    }
  }
  {
    int r = t >> 2, c0 = (t & 3) * 16;
    int n = n0 + r;
    bool rok = n < NN;
    const float4* src = (const float4*)(x + (size_t)n * FF + c0);
    float flr = scb[128];
    #pragma unroll
    for (int c4 = 0; c4 < 4; c4++) {
      float4 v = rok ? src[c4] : make_float4(0.f, 0.f, 0.f, 0.f);
      float4 sc = ((const float4*)scb)[(c0 >> 2) + c4];
      float4 of = ((const float4*)(scb + 64))[(c0 >> 2) + c4];
      v.x = fmaxf(v.x * sc.x + of.x, flr);
      v.y = fmaxf(v.y * sc.y + of.y, flr);
      v.z = fmaxf(v.z * sc.z + of.z, flr);
      v.w = fmaxf(v.w * sc.w + of.w, flr);
      ushort4 h4, l4;
      split4(v, h4, l4);
      *(ushort4*)&Ah[r * 72 + c0 + c4 * 4] = h4;
      *(ushort4*)&Al[r * 72 + c0 + c4 * 4] = l4;
    }
  }
  __syncthreads();
  int lane = t & 63;
  int l15 = lane & 15;
  int quad = lane >> 4;
  int w = __builtin_amdgcn_readfirstlane(t >> 6);
  int rbase = (w & 1) * 32;
  int cbase = (w >> 1) * 64;
  f32x4 acc[2][4];
  #pragma unroll
  for (int rt = 0; rt < 2; rt++)
    #pragma unroll
    for (int ct = 0; ct < 4; ct++) acc[rt][ct] = (f32x4){0.f, 0.f, 0.f, 0.f};

  #pragma unroll
  for (int ks = 0; ks < 2; ks++) {
    bf16x8 a_h[2], a_l[2];
    #pragma unroll
    for (int rt = 0; rt < 2; rt++) {
      int row = rbase + rt * 16 + l15;
      a_h[rt] = *(const bf16x8*)&Ah[row * 72 + ks * 32 + quad * 8];
      a_l[rt] = *(const bf16x8*)&Al[row * 72 + ks * 32 + quad * 8];
    }
    #pragma unroll
    for (int ct = 0; ct < 4; ct++) {
      int col = cbase + ct * 16 + l15;
      bf16x8 b_h = *(const bf16x8*)&Bh[col * 72 + ks * 32 + quad * 8];
      bf16x8 b_l = *(const bf16x8*)&Bl[col * 72 + ks * 32 + quad * 8];
      #pragma unroll
      for (int rt = 0; rt < 2; rt++) {
        acc[rt][ct] = __builtin_amdgcn_mfma_f32_16x16x32_bf16(a_h[rt], b_h, acc[rt][ct], 0, 0, 0);
        acc[rt][ct] = __builtin_amdgcn_mfma_f32_16x16x32_bf16(a_h[rt], b_l, acc[rt][ct], 0, 0, 0);
        acc[rt][ct] = __builtin_amdgcn_mfma_f32_16x16x32_bf16(a_l[rt], b_h, acc[rt][ct], 0, 0, 0);
      }
    }
  }
  // store: cols 0..63 -> Xd (f32), 64..127 -> Xs (bf16)
  #pragma unroll
  for (int rt = 0; rt < 2; rt++) {
    #pragma unroll
    for (int ct = 0; ct < 4; ct++) {
      int col = cbase + ct * 16 + l15;
      #pragma unroll
      for (int reg = 0; reg < 4; reg++) {
        int n = n0 + rbase + rt * 16 + quad * 4 + reg;
        if (n < NN) {
          float v = acc[rt][ct][reg];
          if (col < 64) Xd[(size_t)n * FF + col] = v;
          else          Xs[(size_t)n * FF + (col - 64)] = bf_rne(v);
        }
      }
    }
  }
}

// ---------------------------------------------------------------- per-node CSR aggregation (round-3 proven, 67.4 us)
__global__ __launch_bounds__(256) void k_agg(const int* __restrict__ srcs, const int* __restrict__ offsets,
                                             const unsigned int* __restrict__ PermEA,
                                             const unsigned short* __restrict__ MwT_h,
                                             const unsigned short* __restrict__ MwT_l,
                                             const float* __restrict__ bconst,
                                             const float* __restrict__ Xd, const unsigned short* __restrict__ Xs,
                                             unsigned short* __restrict__ aggs) {
  int wid = __builtin_amdgcn_readfirstlane(threadIdx.x >> 6);
  int lane = threadIdx.x & 63;
  int l15 = lane & 15;
  int quad = lane >> 4;
  int n = blockIdx.x * 4 + wid;
  if (n >= NN) return;

  bf16x8 bh[4], bl[4];
  #pragma unroll
  for (int ct = 0; ct < 4; ct++) {
    if (quad < 2) {
      bh[ct] = *(const bf16x8*)&MwT_h[(ct * 16 + l15) * 16 + quad * 8];
      bl[ct] = *(const bf16x8*)&MwT_l[(ct * 16 + l15) * 16 + quad * 8];
    } else {
      bh[ct] = (bf16x8){0, 0, 0, 0, 0, 0, 0, 0};
      bl[ct] = (bf16x8){0, 0, 0, 0, 0, 0, 0, 0};
    }
  }

  float4 xd4 = *(const float4*)(Xd + (size_t)n * FF + 4 * l15);
  float4 bc4 = *(const float4*)(bconst + 4 * l15);
  float bas[4] = {xd4.x + bc4.x, xd4.y + bc4.y, xd4.z + bc4.z, xd4.w + bc4.w};

  int o0 = offsets[n], o1 = offsets[n + 1];
  float s[4]  = {0.f, 0.f, 0.f, 0.f};
  float sq[4] = {0.f, 0.f, 0.f, 0.f};
  float mn[4] = {FLT_MAX, FLT_MAX, FLT_MAX, FLT_MAX};
  float mx[4] = {-FLT_MAX, -FLT_MAX, -FLT_MAX, -FLT_MAX};

  for (int base = o0; base < o1; base += 16) {
    bf16x8 af = (bf16x8){0, 0, 0, 0, 0, 0, 0, 0};
    if (quad < 2) af = *(const bf16x8*)(PermEA + (size_t)(base + l15) * 8 + quad * 4);
    f32x4 acc[4];
    #pragma unroll
    for (int ct = 0; ct < 4; ct++) {
      f32x4 a = (f32x4){0.f, 0.f, 0.f, 0.f};
      a = __builtin_amdgcn_mfma_f32_16x16x32_bf16(af, bl[ct], a, 0, 0, 0);
      a = __builtin_amdgcn_mfma_f32_16x16x32_bf16(af, bh[ct], a, 0, 0, 0);
      acc[ct] = a;
    }
    #pragma unroll
    for (int reg = 0; reg < 4; reg++) {
      int e = base + quad * 4 + reg;
      bool valid = e < o1;
      int ec = min(e, o1 - 1);
      int src = srcs[ec];
      ushort4 xs4 = *(const ushort4*)(Xs + (size_t)src * FF + 4 * l15);
      float xf[4] = {bf_up(xs4.x), bf_up(xs4.y), bf_up(xs4.z), bf_up(xs4.w)};
      #pragma unroll
      for (int ct = 0; ct < 4; ct++) {
        float h = bas[ct] + xf[ct] + acc[ct][reg];
        float hv = valid ? h : 0.0f;
        s[ct] += hv;
        sq[ct] = fmaf(hv, hv, sq[ct]);
        float t1 = fminf(mn[ct], h);
        float t2 = fmaxf(mx[ct], h);
        mn[ct] = valid ? t1 : mn[ct];
        mx[ct] = valid ? t2 : mx[ct];
      }
    }
  }

  #pragma unroll
  for (int ct = 0; ct < 4; ct++) {
    s[ct] += __shfl_xor(s[ct], 16);  s[ct] += __shfl_xor(s[ct], 32);
    sq[ct] += __shfl_xor(sq[ct], 16); sq[ct] += __shfl_xor(sq[ct], 32);
    mn[ct] = fminf(mn[ct], __shfl_xor(mn[ct], 16)); mn[ct] = fminf(mn[ct], __shfl_xor(mn[ct], 32));
    mx[ct] = fmaxf(mx[ct], __shfl_xor(mx[ct], 16)); mx[ct] = fmaxf(mx[ct], __shfl_xor(mx[ct], 32));
  }

  float d = (float)(o1 - o0);
  float dc = fmaxf(d, 1.0f);
  float rdc = 1.0f / dc;
  bool has = d > 0.0f;
  ushort4 outv;
  unsigned short ov[4];
  #pragma unroll
  for (int ct = 0; ct < 4; ct++) {
    float mean = s[ct] * rdc;
    float msq = sq[ct] * rdc;
    float sd = sqrtf(fmaxf(msq - mean * mean, 0.0f) + 1e-5f);
    float vmn = has ? mn[ct] : 0.0f;
    float vmx = has ? mx[ct] : 0.0f;
    float val = (quad == 0) ? mean : (quad == 1) ? vmn : (quad == 2) ? vmx : sd;
    ov[ct] = bf_rne(val);
  }
  outv.x = ov[0]; outv.y = ov[1]; outv.z = ov[2]; outv.w = ov[3];
  *(ushort4*)(aggs + (size_t)n * 256 + quad * 64 + 4 * l15) = outv;
}

// ---------------------------------------------------------------- y = [bn(x),scaled aggs] @ Wcomb + bcomb + BN partials
// LDS-staged A and B (proven pattern). agg blocks staged ONCE raw (no scale/requant);
// amp/att applied in the f32 epilogue via 3 accumulators.
__global__ __launch_bounds__(256) void k_post(const float* __restrict__ x, const float* __restrict__ scb,
                                              const unsigned short* __restrict__ aggs,
                                              const float* __restrict__ amp, const float* __restrict__ att,
                                              const unsigned short* __restrict__ WcT_h,
                                              const unsigned short* __restrict__ WcT_l,
                                              const float* __restrict__ bcomb,
                                              float* __restrict__ y, float* __restrict__ partials) {
  __shared__ unsigned short Ah[64 * 72], Al[64 * 72];
  __shared__ unsigned short Bh[64 * 72], Bl[64 * 72];
  __shared__ float red_s[4][32], red_q[4][32];
  int t = threadIdx.x;
  int n0 = blockIdx.x * 64;
  int lane = t & 63;
  int l15 = lane & 15;
  int quad = lane >> 4;
  int w = __builtin_amdgcn_readfirstlane(t >> 6);
  int rbase = (w & 1) * 32;
  int cbase = (w >> 1) * 32;

  int ar = t >> 2;
  int ac0 = (t & 3) * 16;
  int an = n0 + ar;
  bool rok = an < NN;
  const float* xrow = x + (size_t)an * FF;
  const unsigned short* arow = aggs + (size_t)an * 256;
  float flr = scb[128];

  f32x4 acc[3][2][2];
  #pragma unroll
  for (int s = 0; s < 3; s++)
    #pragma unroll
    for (int rt = 0; rt < 2; rt++)
      #pragma unroll
      for (int ct = 0; ct < 2; ct++) acc[s][rt][ct] = (f32x4){0.f, 0.f, 0.f, 0.f};

  // ---- x chunk: bn(x) hi/lo, B rows 0..63
  {
    #pragma unroll
    for (int c4 = 0; c4 < 4; c4++) {
      float4 v = rok ? *(const float4*)(xrow + ac0 + c4 * 4) : make_float4(0.f, 0.f, 0.f, 0.f);
      float4 sc = ((const float4*)scb)[(ac0 >> 2) + c4];
      float4 of = ((const float4*)(scb + 64))[(ac0 >> 2) + c4];
      v.x = fmaxf(v.x * sc.x + of.x, flr);
      v.y = fmaxf(v.y * sc.y + of.y, flr);
      v.z = fmaxf(v.z * sc.z + of.z, flr);
      v.w = fmaxf(v.w * sc.w + of.w, flr);
      ushort4 h4, l4;
      split4(v, h4, l4);
      *(ushort4*)&Ah[ar * 72 + ac0 + c4 * 4] = h4;
      *(ushort4*)&Al[ar * 72 + ac0 + c4 * 4] = l4;
    }
    const ushort4* sh = (const ushort4*)(WcT_h + ar * 832 + ac0);
    const ushort4* sl = (const ushort4*)(WcT_l + ar * 832 + ac0);
    #pragma unroll
    for (int i = 0; i < 4; i++) {
      *(ushort4*)&Bh[ar * 72 + ac0 + i * 4] = sh[i];
      *(ushort4*)&Bl[ar * 72 + ac0 + i * 4] = sl[i];
    }
    __syncthreads();
    #pragma unroll
    for (int ks = 0; ks < 2; ks++) {
      bf16x8 a_h[2], a_l[2], b_h[2], b_l[2];
      #pragma unroll
      for (int rt = 0; rt < 2; rt++) {
        int row = rbase + rt * 16 + l15;
        a_h[rt] = *(const bf16x8*)&Ah[row * 72 + ks * 32 + quad * 8];
        a_l[rt] = *(const bf16x8*)&Al[row * 72 + ks * 32 + quad * 8];
      }
      #pragma unroll
      for (int ct = 0; ct < 2; ct++) {
        int col = cbase + ct * 16 + l15;
        b_h[ct] = *(const bf16x8*)&Bh[col * 72 + ks * 32 + quad * 8];
        b_l[ct] = *(const bf16x8*)&Bl[col * 72 + ks * 32 + quad * 8];
      }
      #pragma unroll
      for (int rt = 0; rt < 2; rt++)
        #pragma unroll
        for (int ct = 0; ct < 2; ct++) {
          acc[0][rt][ct] = __builtin_amdgcn_mfma_f32_16x16x32_bf16(a_h[rt], b_h[ct], acc[0][rt][ct], 0, 0, 0);
          acc[0][rt][ct] = __builtin_amdgcn_mfma_f32_16x16x32_bf16(a_h[rt], b_l[ct], acc[0][rt][ct], 0, 0, 0);
          acc[0][rt][ct] = __builtin_amdgcn_mfma_f32_16x16x32_bf16(a_l[rt], b_h[ct], acc[0][rt][ct], 0, 0, 0);
        }
    }
    __syncthreads();
  }

  // ---- agg chunks c=0..3 (mean/min/max/std): A staged ONCE raw; 3 B-chunks -> acc[0..2]
  for (int c = 0; c < 4; c++) {
    #pragma unroll
    for (int s = 0; s < 3; s++) {
      if (s == 0) {
        #pragma unroll
        for (int c4 = 0; c4 < 4; c4++) {
          ushort4 u = rok ? *(const ushort4*)(arow + c * 64 + ac0 + c4 * 4) : make_ushort4(0, 0, 0, 0);
          *(ushort4*)&Ah[ar * 72 + ac0 + c4 * 4] = u;
        }
      }
      {
        int kbase = 64 + s * 256 + c * 64;
        const ushort4* sh = (const ushort4*)(WcT_h + ar * 832 + kbase + ac0);
        const ushort4* sl = (const ushort4*)(WcT_l + ar * 832 + kbase + ac0);
        #pragma unroll
        for (int i = 0; i < 4; i++) {
          *(ushort4*)&Bh[ar * 72 + ac0 + i * 4] = sh[i];
          *(ushort4*)&Bl[ar * 72 + ac0 + i * 4] = sl[i];
        }
      }
      __syncthreads();
      #pragma unroll
      for (int ks = 0; ks < 2; ks++) {
        bf16x8 a[2], b_h[2], b_l[2];
        #pragma unroll
        for (int rt = 0; rt < 2; rt++) {
          int row = rbase + rt * 16 + l15;
          a[rt] = *(const bf16x8*)&Ah[row * 72 + ks * 32 + quad * 8];
        }
        #pragma unroll
        for (int ct = 0; ct < 2; ct++) {
          int col = cbase + ct * 16 + l15;
          b_h[ct] = *(const bf16x8*)&Bh[col * 72 + ks * 32 + quad * 8];
          b_l[ct] = *(const bf16x8*)&Bl[col * 72 + ks * 32 + quad * 8];
        }
        #pragma unroll
        for (int rt = 0; rt < 2; rt++)
          #pragma unroll
          for (int ct = 0; ct < 2; ct++) {
            acc[s][rt][ct] = __builtin_amdgcn_mfma_f32_16x16x32_bf16(a[rt], b_h[ct], acc[s][rt][ct], 0, 0, 0);
            acc[s][rt][ct] = __builtin_amdgcn_mfma_f32_16x16x32_bf16(a[rt], b_l[ct], acc[s][rt][ct], 0, 0, 0);
          }
      }
      __syncthreads();
    }
  }

  // epilogue: combine scalings in f32, bias, store y, BN partials
  float ps[2] = {0.f, 0.f}, pq[2] = {0.f, 0.f};
  float bc[2];
  #pragma unroll
  for (int ct = 0; ct < 2; ct++) bc[ct] = bcomb[cbase + ct * 16 + l15];
  #pragma unroll
  for (int rt = 0; rt < 2; rt++) {
    #pragma unroll
    for (int reg = 0; reg < 4; reg++) {
      int n = n0 + rbase + rt * 16 + quad * 4 + reg;
      bool ok = n < NN;
      int nc = min(n, NN - 1);
      float am = amp[nc];
      float at = att[nc];
      #pragma unroll
      for (int ct = 0; ct < 2; ct++) {
        float v = acc[0][rt][ct][reg] + am * acc[1][rt][ct][reg] + at * acc[2][rt][ct][reg] + bc[ct];
        if (ok) {
          y[(size_t)n * FF + (cbase + ct * 16 + l15)] = v;
          ps[ct] += v;
          pq[ct] += v * v;
        }
      }
    }
  }
  #pragma unroll
  for (int ct = 0; ct < 2; ct++) {
    ps[ct] += __shfl_xor(ps[ct], 16);
    ps[ct] += __shfl_xor(ps[ct], 32);
    pq[ct] += __shfl_xor(pq[ct], 16);
    pq[ct] += __shfl_xor(pq[ct], 32);
  }
  if (quad == 0) {
    #pragma unroll
    for (int ct = 0; ct < 2; ct++) {
      red_s[w][ct * 16 + l15] = ps[ct];
      red_q[w][ct * 16 + l15] = pq[ct];
    }
  }
  __syncthreads();
  if (t < 64) {
    float ss, qq;
    if (t < 32) { ss = red_s[0][t] + red_s[1][t]; qq = red_q[0][t] + red_q[1][t]; }
    else        { ss = red_s[2][t - 32] + red_s[3][t - 32]; qq = red_q[2][t - 32] + red_q[3][t - 32]; }
    partials[(size_t)blockIdx.x * 128 + t] = ss;
    partials[(size_t)blockIdx.x * 128 + 64 + t] = qq;
  }
}

// ---------------------------------------------------------------- reduce BN partials -> scb
__global__ __launch_bounds__(1024) void k_bnfin(const float* __restrict__ partials,
                                                const float* __restrict__ gamma, const float* __restrict__ beta,
                                                float* __restrict__ scb) {
  __shared__ float red[1024];
  __shared__ double tot[128];
  int t = threadIdx.x;
  int c = t & 127, seg = t >> 7;
  float s = 0.f;
  for (int i = seg; i < NB64; i += 8) s += partials[(size_t)i * 128 + c];
  red[t] = s;
  __syncthreads();
  if (t < 128) {
    double d = 0.0;
    #pragma unroll
    for (int sg = 0; sg < 8; sg++) d += (double)red[sg * 128 + t];
    tot[t] = d;
  }
  __syncthreads();
  if (t < 64) {
    double mu = tot[t] / (double)NN;
    double var = tot[64 + t] / (double)NN - mu * mu;
    float sc = gamma[t] * rsqrtf((float)fmax(var, 0.0) + 1e-5f);
    scb[t] = sc;
    scb[64 + t] = beta[t] - (float)mu * sc;
  }
  if (t == 0) scb[128] = 0.0f;
}

// ---------------------------------------------------------------- pooling (BN+relu fused)
__global__ __launch_bounds__(256) void k_pool(const float* __restrict__ x, const float* __restrict__ scb,
                                              const int* __restrict__ batch,
                                              float* __restrict__ psum, float* __restrict__ cnt) {
  int lane = threadIdx.x & 63;
  int wv = threadIdx.x >> 6;
  int wglobal = blockIdx.x * 4 + wv;
  int nw = gridDim.x * 4;
  int per = (NN + nw - 1) / nw;
  int n0 = wglobal * per;
  int n1 = min(n0 + per, NN);
  if (n0 >= n1) return;
  float sc = scb[lane], of = scb[64 + lane], flr = scb[128];
  int gcur = batch[n0];
  float acc = 0.0f;
  int count = 0;
  for (int n = n0; n < n1; n++) {
    int g = batch[n];
    float v = fmaxf(x[(size_t)n * FF + lane] * sc + of, flr);
    if (g != gcur) {
      atomicAdd(&psum[gcur * FF + lane], acc);
      if (lane == 0) atomicAdd(&cnt[gcur], (float)count);
      gcur = g; acc = 0.0f; count = 0;
    }
    acc += v;
    count++;
  }
  atomicAdd(&psum[gcur * FF + lane], acc);
  if (lane == 0) atomicAdd(&cnt[gcur], (float)count);
}

// ---------------------------------------------------------------- final MLP
__global__ void k_final(const float* __restrict__ psum, const float* __restrict__ cnt,
                        const float* __restrict__ W1, const float* __restrict__ b1,
                        const float* __restrict__ W2, const float* __restrict__ b2, float* __restrict__ out) {
  int g = threadIdx.x;
  if (g >= GG) return;
  float c = fmaxf(cnt[g], 1.0f);
  float gm[64];
  #pragma unroll
  for (int i = 0; i < 64; i++) gm[i] = psum[g * FF + i] / c;
  float o = b2[0];
  for (int h = 0; h < 40; h++) {
    float a = b1[h];
    #pragma unroll
    for (int i = 0; i < 64; i++) a += gm[i] * W1[i * 40 + h];
    o += fmaxf(a, 0.0f) * W2[h];
  }
  out[g] = o;
}

// ================================================================ launch
extern "C" void kernel_launch(void* const* d_in, const int* in_sizes, int n_in,
                              void* d_out, int out_size, void* d_ws, size_t ws_size,
                              hipStream_t stream) {
  (void)in_sizes; (void)n_in; (void)out_size; (void)ws_size;
  const float* x0    = (const float*)d_in[0];
  const float* eattr = (const float*)d_in[1];
  const float* We    = (const float*)d_in[2];
  const float* be    = (const float*)d_in[3];
  const float* Wpre  = (const float*)d_in[4];
  const float* bpre  = (const float*)d_in[5];
  const float* Wpost = (const float*)d_in[6];
  const float* bpost = (const float*)d_in[7];
  const float* Wlin  = (const float*)d_in[8];
  const float* blin  = (const float*)d_in[9];
  const float* gamma = (const float*)d_in[10];
  const float* beta  = (const float*)d_in[11];
  const float* W1    = (const float*)d_in[12];
  const float* b1    = (const float*)d_in[13];
  const float* W2    = (const float*)d_in[14];
  const float* b2    = (const float*)d_in[15];
  const int* eidx    = (const int*)d_in[16];
  const int* batch   = (const int*)d_in[17];
  float* out = (float*)d_out;

  char* w = (char*)d_ws;
  size_t off = 0;
  auto alloc = [&](size_t bytes) -> void* {
    void* p = w + off;
    off += bytes;
    off = (off + 255) & ~(size_t)255;
    return p;
  };
  int*    deg     = (int*)alloc(NN * sizeof(int));
  int*    offsets = (int*)alloc((NN + 1) * sizeof(int));
  int*    cursor  = (int*)alloc(NN * sizeof(int));
  int*    srcs    = (int*)alloc((EE + 16) * sizeof(int));
  unsigned int* PermEA = (unsigned int*)alloc(((size_t)EE + 16) * 8 * sizeof(unsigned int));
  int*    bsum    = (int*)alloc(NSB * sizeof(int));
  int*    bpref   = (int*)alloc(NSB * sizeof(int));
  float*  lsum    = (float*)alloc(NSB * sizeof(float));
  float*  meta    = (float*)alloc(sizeof(float));
  float*  amp     = (float*)alloc(NN * sizeof(float));
  float*  att     = (float*)alloc(NN * sizeof(float));
  unsigned short* MwT_h = (unsigned short*)alloc(2 * FF * EDIM * sizeof(unsigned short));
  unsigned short* MwT_l = (unsigned short*)alloc(2 * FF * EDIM * sizeof(unsigned short));
  float*  bconst  = (float*)alloc(2 * FF * sizeof(float));
  float*  bcomb   = (float*)alloc(2 * FF * sizeof(float));
  float*  scbA    = (float*)alloc(129 * sizeof(float));
  float*  scbB    = (float*)alloc(2 * 129 * sizeof(float));
  unsigned short* WcT_h = (unsigned short*)alloc(2 * (size_t)FF * 832 * sizeof(unsigned short));
  unsigned short* WcT_l = (unsigned short*)alloc(2 * (size_t)FF * 832 * sizeof(unsigned short));
  unsigned short* WxT_h = (unsigned short*)alloc(2 * 128 * 64 * sizeof(unsigned short));
  unsigned short* WxT_l = (unsigned short*)alloc(2 * 128 * 64 * sizeof(unsigned short));
  float*  partials = (float*)alloc((size_t)NB64 * 128 * sizeof(float));
  float*  Xd      = (float*)alloc((size_t)NN * FF * sizeof(float));
  unsigned short* Xs = (unsigned short*)alloc((size_t)NN * FF * sizeof(unsigned short));
  unsigned short* aggs = (unsigned short*)alloc((size_t)NN * 256 * sizeof(unsigned short));
  float*  ybuf    = (float*)alloc((size_t)NN * FF * sizeof(float));
  float*  psum    = (float*)alloc((GG * FF + GG) * sizeof(float));
  float*  cnt     = psum + GG * FF;

  k_zfill<<<NSB, 256, 0, stream>>>(deg, cursor, srcs + EE, psum);
  k_deg<<<(EE + 255) / 256, 256, 0, stream>>>(eidx, deg);
  k_scanA<<<NSB, 256, 0, stream>>>(deg, offsets, bsum, lsum);
  k_scanB<<<1, 256, 0, stream>>>(bsum, lsum, bpref, meta, scbA);
  k_scanC<<<NSB, 256, 0, stream>>>(offsets, bpref, deg, meta, amp, att);
  k_scatter<<<(EE + 255) / 256, 256, 0, stream>>>(eidx, offsets, cursor, srcs, eattr, PermEA);
  k_prep2<<<490, 256, 0, stream>>>(We, be, Wpre, bpre, Wpost, bpost, Wlin, blin,
                                   MwT_h, MwT_l, bconst, WcT_h, WcT_l, WxT_h, WxT_l, bcomb);

  const float* xin = x0;
  const float* scb_in = scbA;
  for (int l = 0; l < 2; l++) {
    k_xform<<<NB64, 256, 0, stream>>>(xin, scb_in, WxT_h + l * 8192, WxT_l + l * 8192, Xd, Xs);
    k_agg<<<(NN + 3) / 4, 256, 0, stream>>>(srcs, offsets, PermEA, MwT_h + l * 1024, MwT_l + l * 1024,
                                            bconst + l * FF, Xd, Xs, aggs);
    k_post<<<NB64, 256, 0, stream>>>(xin, scb_in, aggs, amp, att,
                                     WcT_h + (size_t)l * 53248, WcT_l + (size_t)l * 53248,
                                     bcomb + l * FF, ybuf, partials);
    k_bnfin<<<1, 1024, 0, stream>>>(partials, gamma + l * FF, beta + l * FF, scbB + l * 129);
    xin = ybuf;
    scb_in = scbB + l * 129;
  }
  k_pool<<<200, 256, 0, stream>>>(ybuf, scbB + 129, batch, psum, cnt);
  k_final<<<1, 64, 0, stream>>>(psum, cnt, W1, b1, W2, b2, out);
}